// Round 5
// baseline (113.260 us; speedup 1.0000x reference)
//
#include <hip/hip_runtime.h>
#include <math.h>

// Problem constants (fixed by the reference setup_inputs)
#define BB 2
#define VV 3
#define CC 8
#define HH 128
#define WW 160
#define DD 64
constexpr int HW = HH * WW;
constexpr int NPIX = BB * HW;            // 40960
constexpr int PX_PER_BLOCK = 16;         // consecutive pixels per block
constexpr int CHUNKS = 16;               // depth chunks per pixel
constexpr int DEPTHS_PER_CHUNK = DD / CHUNKS;   // 4
constexpr int GRID_FUSED = NPIX / PX_PER_BLOCK; // 2560
constexpr int XCD_STRIDE = GRID_FUSED / 8;      // 320

// ---------------------------------------------------------------------------
// Prep 1: transpose features [V,B,C,H,W] -> [V,B,H,W,C]: one bilinear corner
// becomes 8 contiguous floats (2x float4).
// ---------------------------------------------------------------------------
__global__ __launch_bounds__(256)
void transpose_feats(const float* __restrict__ feats, float* __restrict__ ft)
{
    const int t = blockIdx.x * blockDim.x + threadIdx.x;   // one thread per (vb, hw)
    if (t >= VV * BB * HW) return;
    const int vb = t / HW;
    const int hw = t - vb * HW;
    const float* src = feats + (size_t)vb * CC * HW + hw;
    float* dst = ft + (size_t)vb * HW * CC + (size_t)hw * CC;
    float4 lo, hi;
    lo.x = src[0 * HW]; lo.y = src[1 * HW]; lo.z = src[2 * HW]; lo.w = src[3 * HW];
    hi.x = src[4 * HW]; hi.y = src[5 * HW]; hi.z = src[6 * HW]; hi.w = src[7 * HW];
    ((float4*)dst)[0] = lo;
    ((float4*)dst)[1] = hi;
}

// ---------------------------------------------------------------------------
// Prep 2: transpose depth_values [B,D,H,W] -> dvT [B,H*W,D] via LDS tile so
// the fused kernel loads its 4 depths as one float4 (kills the per-iteration
// serial dv-load -> rcp -> addr dependency).
// Block = 256 threads handles 64 pixels x 64 depths (16.25 KB LDS).
// ---------------------------------------------------------------------------
__global__ __launch_bounds__(256)
void transpose_dv(const float* __restrict__ dv, float* __restrict__ dvT)
{
    __shared__ float tile[64 * 65];      // +1 pad: conflict-free
    const int t   = threadIdx.x;
    const int blk = blockIdx.x;          // 640 = BB * (HW/64)
    const int b   = blk / (HW / 64);
    const int hw0 = (blk % (HW / 64)) * 64;

    const float* src = dv + (size_t)b * DD * HW + hw0;
    const int px = t & 63;
    const int dq = t >> 6;               // 0..3
#pragma unroll
    for (int j = 0; j < 16; ++j) {
        const int d = dq * 16 + j;
        tile[px * 65 + d] = src[(size_t)d * HW + px];   // coalesced 256B reads
    }
    __syncthreads();

    float* dst = dvT + ((size_t)b * HW + hw0) * DD;
    const int c = t & 15;                // chunk of 4 depths
#pragma unroll
    for (int j = 0; j < 4; ++j) {
        const int p = (t >> 4) + j * 16;
        float4 v;
        v.x = tile[p * 65 + c * 4 + 0];
        v.y = tile[p * 65 + c * 4 + 1];
        v.z = tile[p * 65 + c * 4 + 2];
        v.w = tile[p * 65 + c * 4 + 3];
        ((float4*)(dst + (size_t)p * DD))[c] = v;       // fully coalesced writes
    }
}

// ---------------------------------------------------------------------------
// Fused: block = 16 consecutive pixels x 16 depth chunks (4 waves).
// All 4 dv loaded upfront (float4); per depth, BOTH views' 16 corner float4
// loads are issued before any FMA -> high memory-level parallelism.
// No launch_bounds waves-arg, no unroll pragma (round-3 spill lesson).
// ---------------------------------------------------------------------------
__global__ __launch_bounds__(256)
void depthnet_fused(const float* __restrict__ ft,      // [V,B,H,W,C]
                    const float* __restrict__ proj,    // [B,V,3,4]
                    const float* __restrict__ dvT,     // [B,H*W,D]
                    const float* __restrict__ regw,    // [C]
                    float* __restrict__ out)           // [B,H,W]
{
    __shared__ float sm_m[4 * PX_PER_BLOCK];
    __shared__ float sm_l[4 * PX_PER_BLOCK];
    __shared__ float sm_s[4 * PX_PER_BLOCK];

    const int tid   = threadIdx.x;
    const int lane  = tid & 63;
    const int wave  = tid >> 6;              // 0..3
    const int px    = lane & 15;             // pixel within block
    const int sub   = lane >> 4;             // 0..3
    const int chunk = wave * 4 + sub;        // 0..15
    // XCD swizzle: contiguous pixel band per XCD for L2 locality
    const int bswz  = (blockIdx.x & 7) * XCD_STRIDE + (blockIdx.x >> 3);
    const int pixel = bswz * PX_PER_BLOCK + px;

    const int b  = (pixel >= HW) ? 1 : 0;
    const int hw = pixel - b * HW;
    const int h  = hw / WW;
    const int w  = hw - h * WW;

    // reference-view features (channel-contiguous)
    const float* f0 = ft + ((size_t)b * HW + hw) * CC;
    float rf[CC], rf2[CC];
    {
        float4 lo = ((const float4*)f0)[0];
        float4 hi = ((const float4*)f0)[1];
        rf[0] = lo.x; rf[1] = lo.y; rf[2] = lo.z; rf[3] = lo.w;
        rf[4] = hi.x; rf[5] = hi.y; rf[6] = hi.z; rf[7] = hi.w;
    }
#pragma unroll
    for (int c = 0; c < CC; ++c) rf2[c] = rf[c] * rf[c];

    // per-view projection rows applied to (x, y, 1); T columns
    float Rp[2][3], Tv[2][3];
    const float xf = (float)w, yf = (float)h;
#pragma unroll
    for (int v = 0; v < 2; ++v) {
        const float* M = proj + ((size_t)b * VV + (v + 1)) * 12;
#pragma unroll
        for (int i = 0; i < 3; ++i) {
            Rp[v][i] = M[i * 4 + 0] * xf + M[i * 4 + 1] * yf + M[i * 4 + 2];
            Tv[v][i] = M[i * 4 + 3];
        }
    }

    const float* fsrc0 = ft + ((size_t)(1 * BB + b)) * HW * CC;
    const float* fsrc1 = ft + ((size_t)(2 * BB + b)) * HW * CC;

    // all 4 depths of this chunk: one coalesced float4, rcp upfront
    const float4 dv4 = *(const float4*)(dvT + ((size_t)b * HW + hw) * DD + chunk * 4);
    float dvv[4] = {dv4.x, dv4.y, dv4.z, dv4.w};
    float inv[4];
#pragma unroll
    for (int k = 0; k < 4; ++k) inv[k] = __builtin_amdgcn_rcpf(dvv[k]);

    float m = -INFINITY, l = 0.f, s = 0.f;

    for (int dd = 0; dd < DEPTHS_PER_CHUNK; ++dd) {
        const float dv = dvv[dd];
        const float inv_dv = inv[dd];

        // ---- addresses + weights for BOTH views (no loads yet) ----
        float wt[2][4];
        int   ib[2][4];
        float nmask = 1.0f;
#pragma unroll
        for (int v = 0; v < 2; ++v) {
            const float sx = Rp[v][0] + Tv[v][0] * inv_dv;
            const float sy = Rp[v][1] + Tv[v][1] * inv_dv;
            const float sz = Rp[v][2] + Tv[v][2] * inv_dv;
            const float rsz = __builtin_amdgcn_rcpf(sz);
            const float ix = sx * rsz;       // == (gx+1)*0.5*(W-1)
            const float iy = sy * rsz;
            nmask += ((ix > 0.f) && (ix < (float)(WW - 1)) &&
                      (iy > 0.f) && (iy < (float)(HH - 1))) ? 1.0f : 0.0f;
            const float x0f = floorf(ix), y0f = floorf(iy);
            const float wx1 = ix - x0f, wy1 = iy - y0f;
            const float wx0 = 1.f - wx1, wy0 = 1.f - wy1;
            const float x1f = x0f + 1.f, y1f = y0f + 1.f;
            const bool vx0 = (x0f >= 0.f) && (x0f <= (float)(WW - 1));
            const bool vx1 = (x1f >= 0.f) && (x1f <= (float)(WW - 1));
            const bool vy0 = (y0f >= 0.f) && (y0f <= (float)(HH - 1));
            const bool vy1 = (y1f >= 0.f) && (y1f <= (float)(HH - 1));
            wt[v][0] = wx0 * wy0 * ((vx0 && vy0) ? 1.f : 0.f);
            wt[v][1] = wx1 * wy0 * ((vx1 && vy0) ? 1.f : 0.f);
            wt[v][2] = wx0 * wy1 * ((vx0 && vy1) ? 1.f : 0.f);
            wt[v][3] = wx1 * wy1 * ((vx1 && vy1) ? 1.f : 0.f);
            const int x0c = (int)fminf(fmaxf(x0f, 0.f), (float)(WW - 1));
            const int x1c = (int)fminf(fmaxf(x1f, 0.f), (float)(WW - 1));
            const int y0c = (int)fminf(fmaxf(y0f, 0.f), (float)(HH - 1));
            const int y1c = (int)fminf(fmaxf(y1f, 0.f), (float)(HH - 1));
            ib[v][0] = (y0c * WW + x0c) * CC;
            ib[v][1] = (y0c * WW + x1c) * CC;
            ib[v][2] = (y1c * WW + x0c) * CC;
            ib[v][3] = (y1c * WW + x1c) * CC;
        }

        // ---- issue ALL 16 corner float4 loads before any FMA ----
        float4 a0lo = *(const float4*)(fsrc0 + ib[0][0]);
        float4 a0hi = *(const float4*)(fsrc0 + ib[0][0] + 4);
        float4 a1lo = *(const float4*)(fsrc0 + ib[0][1]);
        float4 a1hi = *(const float4*)(fsrc0 + ib[0][1] + 4);
        float4 a2lo = *(const float4*)(fsrc0 + ib[0][2]);
        float4 a2hi = *(const float4*)(fsrc0 + ib[0][2] + 4);
        float4 a3lo = *(const float4*)(fsrc0 + ib[0][3]);
        float4 a3hi = *(const float4*)(fsrc0 + ib[0][3] + 4);
        float4 b0lo = *(const float4*)(fsrc1 + ib[1][0]);
        float4 b0hi = *(const float4*)(fsrc1 + ib[1][0] + 4);
        float4 b1lo = *(const float4*)(fsrc1 + ib[1][1]);
        float4 b1hi = *(const float4*)(fsrc1 + ib[1][1] + 4);
        float4 b2lo = *(const float4*)(fsrc1 + ib[1][2]);
        float4 b2hi = *(const float4*)(fsrc1 + ib[1][2] + 4);
        float4 b3lo = *(const float4*)(fsrc1 + ib[1][3]);
        float4 b3hi = *(const float4*)(fsrc1 + ib[1][3] + 4);

        // ---- FMA chains ----
        float sum[CC], sq[CC];
#pragma unroll
        for (int c = 0; c < CC; ++c) { sum[c] = rf[c]; sq[c] = rf2[c]; }

        float va[CC], vb[CC];
        va[0] = a0lo.x * wt[0][0] + a1lo.x * wt[0][1] + a2lo.x * wt[0][2] + a3lo.x * wt[0][3];
        va[1] = a0lo.y * wt[0][0] + a1lo.y * wt[0][1] + a2lo.y * wt[0][2] + a3lo.y * wt[0][3];
        va[2] = a0lo.z * wt[0][0] + a1lo.z * wt[0][1] + a2lo.z * wt[0][2] + a3lo.z * wt[0][3];
        va[3] = a0lo.w * wt[0][0] + a1lo.w * wt[0][1] + a2lo.w * wt[0][2] + a3lo.w * wt[0][3];
        va[4] = a0hi.x * wt[0][0] + a1hi.x * wt[0][1] + a2hi.x * wt[0][2] + a3hi.x * wt[0][3];
        va[5] = a0hi.y * wt[0][0] + a1hi.y * wt[0][1] + a2hi.y * wt[0][2] + a3hi.y * wt[0][3];
        va[6] = a0hi.z * wt[0][0] + a1hi.z * wt[0][1] + a2hi.z * wt[0][2] + a3hi.z * wt[0][3];
        va[7] = a0hi.w * wt[0][0] + a1hi.w * wt[0][1] + a2hi.w * wt[0][2] + a3hi.w * wt[0][3];
        vb[0] = b0lo.x * wt[1][0] + b1lo.x * wt[1][1] + b2lo.x * wt[1][2] + b3lo.x * wt[1][3];
        vb[1] = b0lo.y * wt[1][0] + b1lo.y * wt[1][1] + b2lo.y * wt[1][2] + b3lo.y * wt[1][3];
        vb[2] = b0lo.z * wt[1][0] + b1lo.z * wt[1][1] + b2lo.z * wt[1][2] + b3lo.z * wt[1][3];
        vb[3] = b0lo.w * wt[1][0] + b1lo.w * wt[1][1] + b2lo.w * wt[1][2] + b3lo.w * wt[1][3];
        vb[4] = b0hi.x * wt[1][0] + b1hi.x * wt[1][1] + b2hi.x * wt[1][2] + b3hi.x * wt[1][3];
        vb[5] = b0hi.y * wt[1][0] + b1hi.y * wt[1][1] + b2hi.y * wt[1][2] + b3hi.y * wt[1][3];
        vb[6] = b0hi.z * wt[1][0] + b1hi.z * wt[1][1] + b2hi.z * wt[1][2] + b3hi.z * wt[1][3];
        vb[7] = b0hi.w * wt[1][0] + b1hi.w * wt[1][1] + b2hi.w * wt[1][2] + b3hi.w * wt[1][3];

#pragma unroll
        for (int c = 0; c < CC; ++c) {
            sum[c] += va[c] + vb[c];
            sq[c]  += va[c] * va[c] + vb[c] * vb[c];
        }

        const float cnt = __builtin_amdgcn_rcpf(nmask);
        float t1 = 0.f, t2 = 0.f;
#pragma unroll
        for (int c = 0; c < CC; ++c) {
            t1 += regw[c] * sq[c];                    // regw wave-uniform -> scalar
            t2 += (regw[c] * sum[c]) * sum[c];
        }
        const float cost = cnt * t1 - (cnt * cnt) * t2;

        // branch-free online softmax update, weighted by dv
        const float M = fmaxf(m, cost);
        const float e_old = __expf(m - M);     // exp(-inf)=0 on first iter
        const float e_new = __expf(cost - M);
        l = l * e_old + e_new;
        s = s * e_old + e_new * dv;
        m = M;
    }

    // merge the 4 chunks within the wave (lanes xor 16, 32)
#pragma unroll
    for (int off = 16; off < 64; off <<= 1) {
        const float m2 = __shfl_xor(m, off, 64);
        const float l2 = __shfl_xor(l, off, 64);
        const float s2 = __shfl_xor(s, off, 64);
        const float M  = fmaxf(m, m2);
        const float e1 = __expf(m - M);
        const float e2 = __expf(m2 - M);
        l = l * e1 + l2 * e2;
        s = s * e1 + s2 * e2;
        m = M;
    }

    if (lane < PX_PER_BLOCK) {
        sm_m[wave * PX_PER_BLOCK + px] = m;
        sm_l[wave * PX_PER_BLOCK + px] = l;
        sm_s[wave * PX_PER_BLOCK + px] = s;
    }
    __syncthreads();

    if (tid < PX_PER_BLOCK) {
        float M = sm_m[tid], L = sm_l[tid], S = sm_s[tid];
#pragma unroll
        for (int wv = 1; wv < 4; ++wv) {
            const float m2 = sm_m[wv * PX_PER_BLOCK + tid];
            const float l2 = sm_l[wv * PX_PER_BLOCK + tid];
            const float s2 = sm_s[wv * PX_PER_BLOCK + tid];
            const float Mn = fmaxf(M, m2);
            const float e1 = __expf(M - Mn);
            const float e2 = __expf(m2 - Mn);
            L = L * e1 + l2 * e2;
            S = S * e1 + s2 * e2;
            M = Mn;
        }
        out[bswz * PX_PER_BLOCK + tid] = S / L;
    }
}

extern "C" void kernel_launch(void* const* d_in, const int* in_sizes, int n_in,
                              void* d_out, int out_size, void* d_ws, size_t ws_size,
                              hipStream_t stream) {
    const float* feats  = (const float*)d_in[0];
    const float* proj   = (const float*)d_in[1];
    const float* depthv = (const float*)d_in[2];
    const float* regw   = (const float*)d_in[3];
    float* out = (float*)d_out;
    float* ft  = (float*)d_ws;                         // [V,B,H,W,C] = 983040 f
    float* dvT = (float*)d_ws + (size_t)VV * BB * HW * CC;  // [B,HW,D] = 2621440 f

    {
        const int n = VV * BB * HW;                    // 122880
        hipLaunchKernelGGL(transpose_feats, dim3((n + 255) / 256), dim3(256), 0, stream,
                           feats, ft);
    }
    {
        const int grid = BB * (HW / 64);               // 640
        hipLaunchKernelGGL(transpose_dv, dim3(grid), dim3(256), 0, stream,
                           depthv, dvT);
    }
    {
        hipLaunchKernelGGL(depthnet_fused, dim3(GRID_FUSED), dim3(256), 0, stream,
                           ft, proj, dvT, regw, out);
    }
}

// Round 6
// 103.041 us; speedup vs baseline: 1.0992x; 1.0992x over previous
//
#include <hip/hip_runtime.h>
#include <math.h>

// Problem constants (fixed by the reference setup_inputs)
#define BB 2
#define VV 3
#define CC 8
#define HH 128
#define WW 160
#define DD 64
constexpr int HW = HH * WW;
constexpr int NPIX = BB * HW;            // 40960
constexpr int PX_PER_BLOCK = 16;         // consecutive pixels per block
constexpr int CHUNKS = 16;               // depth chunks per pixel
constexpr int DEPTHS_PER_CHUNK = DD / CHUNKS;   // 4
constexpr int GRID_FUSED = NPIX / PX_PER_BLOCK; // 2560
constexpr int XCD_STRIDE = GRID_FUSED / 8;      // 320

typedef _Float16 h8 __attribute__((ext_vector_type(8)));

static __device__ __forceinline__ h8 splat8(float x) {
    const _Float16 v = (_Float16)x;
    h8 r = {v, v, v, v, v, v, v, v};
    return r;
}

// ---------------------------------------------------------------------------
// Prep 1: transpose+quantize features [V,B,C,H,W] fp32 -> [V,B,H*W] h8 (fp16).
// One bilinear corner = one 16B load. Halves L1 bytes AND VMEM instructions.
// ---------------------------------------------------------------------------
__global__ __launch_bounds__(256)
void transpose_feats(const float* __restrict__ feats, h8* __restrict__ ft)
{
    const int t = blockIdx.x * blockDim.x + threadIdx.x;   // one thread per (vb, hw)
    if (t >= VV * BB * HW) return;
    const int vb = t / HW;
    const int hw = t - vb * HW;
    const float* src = feats + (size_t)vb * CC * HW + hw;
    h8 v;
#pragma unroll
    for (int c = 0; c < CC; ++c) v[c] = (_Float16)src[(size_t)c * HW];
    ft[(size_t)vb * HW + hw] = v;
}

// ---------------------------------------------------------------------------
// Prep 2: transpose depth_values [B,D,H,W] -> dvT [B,H*W,D] via LDS tile so
// the fused kernel loads its 4 depths as one float4.
// ---------------------------------------------------------------------------
__global__ __launch_bounds__(256)
void transpose_dv(const float* __restrict__ dv, float* __restrict__ dvT)
{
    __shared__ float tile[64 * 65];      // +1 pad: conflict-free
    const int t   = threadIdx.x;
    const int blk = blockIdx.x;          // 640 = BB * (HW/64)
    const int b   = blk / (HW / 64);
    const int hw0 = (blk % (HW / 64)) * 64;

    const float* src = dv + (size_t)b * DD * HW + hw0;
    const int px = t & 63;
    const int dq = t >> 6;               // 0..3
#pragma unroll
    for (int j = 0; j < 16; ++j) {
        const int d = dq * 16 + j;
        tile[px * 65 + d] = src[(size_t)d * HW + px];   // coalesced 256B reads
    }
    __syncthreads();

    float* dst = dvT + ((size_t)b * HW + hw0) * DD;
    const int c = t & 15;                // chunk of 4 depths
#pragma unroll
    for (int j = 0; j < 4; ++j) {
        const int p = (t >> 4) + j * 16;
        float4 v;
        v.x = tile[p * 65 + c * 4 + 0];
        v.y = tile[p * 65 + c * 4 + 1];
        v.z = tile[p * 65 + c * 4 + 2];
        v.w = tile[p * 65 + c * 4 + 3];
        ((float4*)(dst + (size_t)p * DD))[c] = v;       // fully coalesced writes
    }
}

// ---------------------------------------------------------------------------
// Fused: block = 16 consecutive pixels x 16 depth chunks (4 waves).
// fp16 features: each corner is ONE 16B load; packed-f16 interpolation,
// fp32 sum/sq accumulation. dv float4 prefetch; XCD swizzle for L2 locality.
// ---------------------------------------------------------------------------
__global__ __launch_bounds__(256)
void depthnet_fused(const h8* __restrict__ ft,         // [V,B,H*W] fp16x8
                    const float* __restrict__ proj,    // [B,V,3,4]
                    const float* __restrict__ dvT,     // [B,H*W,D]
                    const float* __restrict__ regw,    // [C]
                    float* __restrict__ out)           // [B,H,W]
{
    __shared__ float sm_m[4 * PX_PER_BLOCK];
    __shared__ float sm_l[4 * PX_PER_BLOCK];
    __shared__ float sm_s[4 * PX_PER_BLOCK];

    const int tid   = threadIdx.x;
    const int lane  = tid & 63;
    const int wave  = tid >> 6;              // 0..3
    const int px    = lane & 15;             // pixel within block
    const int sub   = lane >> 4;             // 0..3
    const int chunk = wave * 4 + sub;        // 0..15
    // XCD swizzle: contiguous pixel band per XCD for L2 locality
    const int bswz  = (blockIdx.x & 7) * XCD_STRIDE + (blockIdx.x >> 3);
    const int pixel = bswz * PX_PER_BLOCK + px;

    const int b  = (pixel >= HW) ? 1 : 0;
    const int hw = pixel - b * HW;
    const int h  = hw / WW;
    const int w  = hw - h * WW;

    // reference-view features (one 16B fp16 load)
    float rf[CC], rf2[CC];
    {
        h8 rv = ft[(size_t)b * HW + hw];
#pragma unroll
        for (int c = 0; c < CC; ++c) { rf[c] = (float)rv[c]; rf2[c] = rf[c] * rf[c]; }
    }

    // per-view projection rows applied to (x, y, 1); T columns
    float Rp[2][3], Tv[2][3];
    const float xf = (float)w, yf = (float)h;
#pragma unroll
    for (int v = 0; v < 2; ++v) {
        const float* M = proj + ((size_t)b * VV + (v + 1)) * 12;
#pragma unroll
        for (int i = 0; i < 3; ++i) {
            Rp[v][i] = M[i * 4 + 0] * xf + M[i * 4 + 1] * yf + M[i * 4 + 2];
            Tv[v][i] = M[i * 4 + 3];
        }
    }

    const h8* fsrc0 = ft + (size_t)(1 * BB + b) * HW;
    const h8* fsrc1 = ft + (size_t)(2 * BB + b) * HW;

    // all 4 depths of this chunk: one coalesced float4, rcp upfront
    const float4 dv4 = *(const float4*)(dvT + ((size_t)b * HW + hw) * DD + chunk * 4);
    float dvv[4] = {dv4.x, dv4.y, dv4.z, dv4.w};
    float inv[4];
#pragma unroll
    for (int k = 0; k < 4; ++k) inv[k] = __builtin_amdgcn_rcpf(dvv[k]);

    float m = -INFINITY, l = 0.f, s = 0.f;

    for (int dd = 0; dd < DEPTHS_PER_CHUNK; ++dd) {
        const float dv = dvv[dd];
        const float inv_dv = inv[dd];

        // ---- addresses + weights for BOTH views (no loads yet) ----
        float wt[2][4];
        int   ib[2][4];
        float nmask = 1.0f;
#pragma unroll
        for (int v = 0; v < 2; ++v) {
            const float sx = Rp[v][0] + Tv[v][0] * inv_dv;
            const float sy = Rp[v][1] + Tv[v][1] * inv_dv;
            const float sz = Rp[v][2] + Tv[v][2] * inv_dv;
            const float rsz = __builtin_amdgcn_rcpf(sz);
            const float ix = sx * rsz;       // == (gx+1)*0.5*(W-1)
            const float iy = sy * rsz;
            nmask += ((ix > 0.f) && (ix < (float)(WW - 1)) &&
                      (iy > 0.f) && (iy < (float)(HH - 1))) ? 1.0f : 0.0f;
            const float x0f = floorf(ix), y0f = floorf(iy);
            const float wx1 = ix - x0f, wy1 = iy - y0f;
            const float wx0 = 1.f - wx1, wy0 = 1.f - wy1;
            const float x1f = x0f + 1.f, y1f = y0f + 1.f;
            const bool vx0 = (x0f >= 0.f) && (x0f <= (float)(WW - 1));
            const bool vx1 = (x1f >= 0.f) && (x1f <= (float)(WW - 1));
            const bool vy0 = (y0f >= 0.f) && (y0f <= (float)(HH - 1));
            const bool vy1 = (y1f >= 0.f) && (y1f <= (float)(HH - 1));
            wt[v][0] = wx0 * wy0 * ((vx0 && vy0) ? 1.f : 0.f);
            wt[v][1] = wx1 * wy0 * ((vx1 && vy0) ? 1.f : 0.f);
            wt[v][2] = wx0 * wy1 * ((vx0 && vy1) ? 1.f : 0.f);
            wt[v][3] = wx1 * wy1 * ((vx1 && vy1) ? 1.f : 0.f);
            const int x0c = (int)fminf(fmaxf(x0f, 0.f), (float)(WW - 1));
            const int x1c = (int)fminf(fmaxf(x1f, 0.f), (float)(WW - 1));
            const int y0c = (int)fminf(fmaxf(y0f, 0.f), (float)(HH - 1));
            const int y1c = (int)fminf(fmaxf(y1f, 0.f), (float)(HH - 1));
            ib[v][0] = y0c * WW + x0c;
            ib[v][1] = y0c * WW + x1c;
            ib[v][2] = y1c * WW + x0c;
            ib[v][3] = y1c * WW + x1c;
        }

        // ---- issue ALL 8 corner 16B loads before any math ----
        h8 a0 = fsrc0[ib[0][0]];
        h8 a1 = fsrc0[ib[0][1]];
        h8 a2 = fsrc0[ib[0][2]];
        h8 a3 = fsrc0[ib[0][3]];
        h8 b0 = fsrc1[ib[1][0]];
        h8 b1 = fsrc1[ib[1][1]];
        h8 b2 = fsrc1[ib[1][2]];
        h8 b3 = fsrc1[ib[1][3]];

        // ---- packed-f16 bilinear interp, fp32 accumulation ----
        h8 vah = a0 * splat8(wt[0][0]) + a1 * splat8(wt[0][1])
               + a2 * splat8(wt[0][2]) + a3 * splat8(wt[0][3]);
        h8 vbh = b0 * splat8(wt[1][0]) + b1 * splat8(wt[1][1])
               + b2 * splat8(wt[1][2]) + b3 * splat8(wt[1][3]);

        float sum[CC], sq[CC];
#pragma unroll
        for (int c = 0; c < CC; ++c) {
            const float av = (float)vah[c];
            const float bv = (float)vbh[c];
            sum[c] = rf[c] + av + bv;
            sq[c]  = rf2[c] + av * av + bv * bv;
        }

        const float cnt = __builtin_amdgcn_rcpf(nmask);
        float t1 = 0.f, t2 = 0.f;
#pragma unroll
        for (int c = 0; c < CC; ++c) {
            t1 += regw[c] * sq[c];                    // regw wave-uniform -> scalar
            t2 += (regw[c] * sum[c]) * sum[c];
        }
        const float cost = cnt * t1 - (cnt * cnt) * t2;

        // branch-free online softmax update, weighted by dv
        const float M = fmaxf(m, cost);
        const float e_old = __expf(m - M);     // exp(-inf)=0 on first iter
        const float e_new = __expf(cost - M);
        l = l * e_old + e_new;
        s = s * e_old + e_new * dv;
        m = M;
    }

    // merge the 4 chunks within the wave (lanes xor 16, 32)
#pragma unroll
    for (int off = 16; off < 64; off <<= 1) {
        const float m2 = __shfl_xor(m, off, 64);
        const float l2 = __shfl_xor(l, off, 64);
        const float s2 = __shfl_xor(s, off, 64);
        const float M  = fmaxf(m, m2);
        const float e1 = __expf(m - M);
        const float e2 = __expf(m2 - M);
        l = l * e1 + l2 * e2;
        s = s * e1 + s2 * e2;
        m = M;
    }

    if (lane < PX_PER_BLOCK) {
        sm_m[wave * PX_PER_BLOCK + px] = m;
        sm_l[wave * PX_PER_BLOCK + px] = l;
        sm_s[wave * PX_PER_BLOCK + px] = s;
    }
    __syncthreads();

    if (tid < PX_PER_BLOCK) {
        float M = sm_m[tid], L = sm_l[tid], S = sm_s[tid];
#pragma unroll
        for (int wv = 1; wv < 4; ++wv) {
            const float m2 = sm_m[wv * PX_PER_BLOCK + tid];
            const float l2 = sm_l[wv * PX_PER_BLOCK + tid];
            const float s2 = sm_s[wv * PX_PER_BLOCK + tid];
            const float Mn = fmaxf(M, m2);
            const float e1 = __expf(M - Mn);
            const float e2 = __expf(m2 - Mn);
            L = L * e1 + l2 * e2;
            S = S * e1 + s2 * e2;
            M = Mn;
        }
        out[bswz * PX_PER_BLOCK + tid] = S / L;
    }
}

extern "C" void kernel_launch(void* const* d_in, const int* in_sizes, int n_in,
                              void* d_out, int out_size, void* d_ws, size_t ws_size,
                              hipStream_t stream) {
    const float* feats  = (const float*)d_in[0];
    const float* proj   = (const float*)d_in[1];
    const float* depthv = (const float*)d_in[2];
    const float* regw   = (const float*)d_in[3];
    float* out = (float*)d_out;
    h8*    ft  = (h8*)d_ws;                            // [V,B,HW] fp16x8 = 1.97 MB
    float* dvT = (float*)d_ws + (size_t)VV * BB * HW * CC / 2;  // [B,HW,D] fp32

    {
        const int n = VV * BB * HW;                    // 122880
        hipLaunchKernelGGL(transpose_feats, dim3((n + 255) / 256), dim3(256), 0, stream,
                           feats, ft);
    }
    {
        const int grid = BB * (HW / 64);               // 640
        hipLaunchKernelGGL(transpose_dv, dim3(grid), dim3(256), 0, stream,
                           depthv, dvT);
    }
    {
        hipLaunchKernelGGL(depthnet_fused, dim3(GRID_FUSED), dim3(256), 0, stream,
                           ft, proj, dvT, regw, out);
    }
}

// Round 7
// 102.982 us; speedup vs baseline: 1.0998x; 1.0006x over previous
//
#include <hip/hip_runtime.h>
#include <math.h>

// Problem constants (fixed by the reference setup_inputs)
#define BB 2
#define VV 3
#define CC 8
#define HH 128
#define WW 160
#define DD 64
constexpr int HW = HH * WW;
constexpr int NPIX = BB * HW;             // 40960
constexpr int PIXBANDS = NPIX / 256;      // 160 blocks of 256 px
constexpr int BANDS_PER_XCD = PIXBANDS / 8;  // 20

typedef _Float16 h8 __attribute__((ext_vector_type(8)));

static __device__ __forceinline__ h8 splat8(float x) {
    const _Float16 v = (_Float16)x;
    h8 r = {v, v, v, v, v, v, v, v};
    return r;
}

// ---------------------------------------------------------------------------
// Prep: transpose+quantize features [V,B,C,H,W] fp32 -> [V,B,H*W] h8 (fp16).
// One bilinear corner = one 16B load.
// ---------------------------------------------------------------------------
__global__ __launch_bounds__(256)
void transpose_feats(const float* __restrict__ feats, h8* __restrict__ ft)
{
    const int t = blockIdx.x * blockDim.x + threadIdx.x;   // one thread per (vb, hw)
    if (t >= VV * BB * HW) return;
    const int vb = t / HW;
    const int hw = t - vb * HW;
    const float* src = feats + (size_t)vb * CC * HW + hw;
    h8 v;
#pragma unroll
    for (int c = 0; c < CC; ++c) v[c] = (_Float16)src[(size_t)c * HW];
    ft[(size_t)vb * HW + hw] = v;
}

// ---------------------------------------------------------------------------
// Cost kernel: ONE thread per (pixel, depth). 2.62M threads -> 160 waves/CU
// of work, no depth loop, no softmax chain. Wave = 64 consecutive pixels at
// one depth: dv load + cost store perfectly coalesced; corner gathers span
// ~1KB contiguous. XCD swizzle: all depths of a pixel band group share an XCD.
// ---------------------------------------------------------------------------
__global__ __launch_bounds__(256)
void cost_kernel(const h8* __restrict__ ft,         // [V,B,H*W] fp16x8
                 const float* __restrict__ proj,    // [B,V,3,4]
                 const float* __restrict__ depthv,  // [B,D,H,W]
                 const float* __restrict__ regw,    // [C]
                 float* __restrict__ cost_out)      // [B,D,H*W]
{
    // swizzle: xcd = blockIdx & 7 gets a contiguous 20-band pixel group,
    // iterating all 64 depths over that group (feature reuse in its L2).
    const int i    = blockIdx.x;
    const int xcd  = i & 7;
    const int idx  = i >> 3;                       // 0..1279
    const int band = xcd * BANDS_PER_XCD + (idx % BANDS_PER_XCD);
    const int d    = idx / BANDS_PER_XCD;          // 0..63
    const int pixel = band * 256 + threadIdx.x;

    const int b  = (pixel >= HW) ? 1 : 0;          // uniform per block
    const int hw = pixel - b * HW;
    const int h  = hw / WW;
    const int w  = hw - h * WW;

    // reference-view features (one 16B fp16 load)
    float rf[CC], rf2[CC];
    {
        h8 rv = ft[(size_t)b * HW + hw];
#pragma unroll
        for (int c = 0; c < CC; ++c) { rf[c] = (float)rv[c]; rf2[c] = rf[c] * rf[c]; }
    }

    // per-view projection rows applied to (x, y, 1); T columns
    float Rp[2][3], Tv[2][3];
    const float xf = (float)w, yf = (float)h;
#pragma unroll
    for (int v = 0; v < 2; ++v) {
        const float* M = proj + ((size_t)b * VV + (v + 1)) * 12;
#pragma unroll
        for (int j = 0; j < 3; ++j) {
            Rp[v][j] = M[j * 4 + 0] * xf + M[j * 4 + 1] * yf + M[j * 4 + 2];
            Tv[v][j] = M[j * 4 + 3];
        }
    }

    const h8* fsrc0 = ft + (size_t)(1 * BB + b) * HW;
    const h8* fsrc1 = ft + (size_t)(2 * BB + b) * HW;

    // dv: coalesced 256B wave load from native layout
    const float dv = depthv[(size_t)b * DD * HW + (size_t)d * HW + hw];
    const float inv_dv = __builtin_amdgcn_rcpf(dv);

    // ---- addresses + weights for BOTH views ----
    float wt[2][4];
    int   ib[2][4];
    float nmask = 1.0f;
#pragma unroll
    for (int v = 0; v < 2; ++v) {
        const float sx = Rp[v][0] + Tv[v][0] * inv_dv;
        const float sy = Rp[v][1] + Tv[v][1] * inv_dv;
        const float sz = Rp[v][2] + Tv[v][2] * inv_dv;
        const float rsz = __builtin_amdgcn_rcpf(sz);
        const float ix = sx * rsz;       // == (gx+1)*0.5*(W-1)
        const float iy = sy * rsz;
        nmask += ((ix > 0.f) && (ix < (float)(WW - 1)) &&
                  (iy > 0.f) && (iy < (float)(HH - 1))) ? 1.0f : 0.0f;
        const float x0f = floorf(ix), y0f = floorf(iy);
        const float wx1 = ix - x0f, wy1 = iy - y0f;
        const float wx0 = 1.f - wx1, wy0 = 1.f - wy1;
        const float x1f = x0f + 1.f, y1f = y0f + 1.f;
        const bool vx0 = (x0f >= 0.f) && (x0f <= (float)(WW - 1));
        const bool vx1 = (x1f >= 0.f) && (x1f <= (float)(WW - 1));
        const bool vy0 = (y0f >= 0.f) && (y0f <= (float)(HH - 1));
        const bool vy1 = (y1f >= 0.f) && (y1f <= (float)(HH - 1));
        wt[v][0] = wx0 * wy0 * ((vx0 && vy0) ? 1.f : 0.f);
        wt[v][1] = wx1 * wy0 * ((vx1 && vy0) ? 1.f : 0.f);
        wt[v][2] = wx0 * wy1 * ((vx0 && vy1) ? 1.f : 0.f);
        wt[v][3] = wx1 * wy1 * ((vx1 && vy1) ? 1.f : 0.f);
        const int x0c = (int)fminf(fmaxf(x0f, 0.f), (float)(WW - 1));
        const int x1c = (int)fminf(fmaxf(x1f, 0.f), (float)(WW - 1));
        const int y0c = (int)fminf(fmaxf(y0f, 0.f), (float)(HH - 1));
        const int y1c = (int)fminf(fmaxf(y1f, 0.f), (float)(HH - 1));
        ib[v][0] = y0c * WW + x0c;
        ib[v][1] = y0c * WW + x1c;
        ib[v][2] = y1c * WW + x0c;
        ib[v][3] = y1c * WW + x1c;
    }

    // ---- issue ALL 8 corner 16B loads before any math ----
    h8 a0 = fsrc0[ib[0][0]];
    h8 a1 = fsrc0[ib[0][1]];
    h8 a2 = fsrc0[ib[0][2]];
    h8 a3 = fsrc0[ib[0][3]];
    h8 b0 = fsrc1[ib[1][0]];
    h8 b1 = fsrc1[ib[1][1]];
    h8 b2 = fsrc1[ib[1][2]];
    h8 b3 = fsrc1[ib[1][3]];

    // ---- packed-f16 bilinear interp, fp32 accumulation ----
    h8 vah = a0 * splat8(wt[0][0]) + a1 * splat8(wt[0][1])
           + a2 * splat8(wt[0][2]) + a3 * splat8(wt[0][3]);
    h8 vbh = b0 * splat8(wt[1][0]) + b1 * splat8(wt[1][1])
           + b2 * splat8(wt[1][2]) + b3 * splat8(wt[1][3]);

    const float cnt = __builtin_amdgcn_rcpf(nmask);
    float t1 = 0.f, t2 = 0.f;
#pragma unroll
    for (int c = 0; c < CC; ++c) {
        const float av = (float)vah[c];
        const float bv = (float)vbh[c];
        const float sum = rf[c] + av + bv;
        const float sq  = rf2[c] + av * av + bv * bv;
        t1 += regw[c] * sq;                        // regw wave-uniform -> scalar
        t2 += (regw[c] * sum) * sum;
    }
    const float cost = cnt * t1 - (cnt * cnt) * t2;

    cost_out[(size_t)b * DD * HW + (size_t)d * HW + hw] = cost;   // coalesced
}

// ---------------------------------------------------------------------------
// Softmax-over-depth kernel: 4 lanes per pixel x 16 depths each, online
// softmax, shuffle merge (xor 16, 32). cost/dv reads coalesced
// (16 consecutive px * 4B = 64B per sub-group).
// ---------------------------------------------------------------------------
__global__ __launch_bounds__(256)
void softmax_depth(const float* __restrict__ cost,    // [B,D,H*W]
                   const float* __restrict__ depthv,  // [B,D,H,W]
                   float* __restrict__ out)           // [B,H,W]
{
    const int t     = blockIdx.x * blockDim.x + threadIdx.x;
    const int lane  = t & 63;
    const int waveg = t >> 6;
    const int px    = lane & 15;
    const int chunk = lane >> 4;               // 0..3
    const int pixel = waveg * 16 + px;

    const int b  = (pixel >= HW) ? 1 : 0;
    const int hw = pixel - b * HW;

    const float* cp = cost   + (size_t)b * DD * HW + hw;
    const float* dp = depthv + (size_t)b * DD * HW + hw;

    float m = -INFINITY, l = 0.f, s = 0.f;
#pragma unroll 4
    for (int j = 0; j < 16; ++j) {
        const int d = chunk * 16 + j;
        const float c  = cp[(size_t)d * HW];
        const float dv = dp[(size_t)d * HW];
        const float M = fmaxf(m, c);
        const float e_old = __expf(m - M);     // exp(-inf)=0 on first iter
        const float e_new = __expf(c - M);
        l = l * e_old + e_new;
        s = s * e_old + e_new * dv;
        m = M;
    }

#pragma unroll
    for (int off = 16; off < 64; off <<= 1) {
        const float m2 = __shfl_xor(m, off, 64);
        const float l2 = __shfl_xor(l, off, 64);
        const float s2 = __shfl_xor(s, off, 64);
        const float M  = fmaxf(m, m2);
        const float e1 = __expf(m - M);
        const float e2 = __expf(m2 - M);
        l = l * e1 + l2 * e2;
        s = s * e1 + s2 * e2;
        m = M;
    }

    if (chunk == 0) out[pixel] = s / l;
}

extern "C" void kernel_launch(void* const* d_in, const int* in_sizes, int n_in,
                              void* d_out, int out_size, void* d_ws, size_t ws_size,
                              hipStream_t stream) {
    const float* feats  = (const float*)d_in[0];
    const float* proj   = (const float*)d_in[1];
    const float* depthv = (const float*)d_in[2];
    const float* regw   = (const float*)d_in[3];
    float* out = (float*)d_out;
    h8*    ft   = (h8*)d_ws;                                  // 1.97 MB
    float* cost = (float*)((char*)d_ws + (size_t)VV * BB * HW * sizeof(h8));  // 10.5 MB

    {
        const int n = VV * BB * HW;                    // 122880
        hipLaunchKernelGGL(transpose_feats, dim3((n + 255) / 256), dim3(256), 0, stream,
                           feats, ft);
    }
    {
        const int grid = DD * PIXBANDS;                // 10240 blocks
        hipLaunchKernelGGL(cost_kernel, dim3(grid), dim3(256), 0, stream,
                           ft, proj, depthv, regw, cost);
    }
    {
        const int total = NPIX * 4;                    // 4 lanes per pixel
        hipLaunchKernelGGL(softmax_depth, dim3(total / 256), dim3(256), 0, stream,
                           cost, depthv, out);
    }
}

// Round 8
// 96.702 us; speedup vs baseline: 1.1712x; 1.0649x over previous
//
#include <hip/hip_runtime.h>
#include <math.h>

// Problem constants (fixed by the reference setup_inputs)
#define BB 2
#define VV 3
#define CC 8
#define HH 128
#define WW 160
#define DD 64
constexpr int HW = HH * WW;
constexpr int NPIX = BB * HW;             // 40960
constexpr int PIXBANDS = NPIX / 256;      // 160 bands of 256 px
constexpr int BANDS_PER_XCD = PIXBANDS / 8;  // 20

typedef _Float16 h8 __attribute__((ext_vector_type(8)));
typedef _Float16 h2 __attribute__((ext_vector_type(2)));

static __device__ __forceinline__ h8 splat8(float x) {
    const _Float16 v = (_Float16)x;
    h8 r = {v, v, v, v, v, v, v, v};
    return r;
}

// ---------------------------------------------------------------------------
// Prep: transpose+quantize features [V,B,C,H,W] fp32 -> [V,B,H*W] h8 (fp16).
// ---------------------------------------------------------------------------
__global__ __launch_bounds__(256)
void transpose_feats(const float* __restrict__ feats, h8* __restrict__ ft)
{
    const int t = blockIdx.x * blockDim.x + threadIdx.x;
    if (t >= VV * BB * HW) return;
    const int vb = t / HW;
    const int hw = t - vb * HW;
    const float* src = feats + (size_t)vb * CC * HW + hw;
    h8 v;
#pragma unroll
    for (int c = 0; c < CC; ++c) v[c] = (_Float16)src[(size_t)c * HW];
    ft[(size_t)vb * HW + hw] = v;
}

// ---------------------------------------------------------------------------
// Cost kernel, DEPTH-PAIR version: one thread per (pixel, depth-pair).
// Adjacent depths sample within ~0.06 px of each other -> corner indices are
// identical ~94% of the time; the d+1 reload runs under a mostly-empty exec
// mask, cutting L1 gather line-traffic ~2x. Emits packed fp16x2 (cost, dv)
// so the softmax pass reads half the bytes.
// ---------------------------------------------------------------------------
__global__ __launch_bounds__(256)
void cost_kernel(const h8* __restrict__ ft,         // [V,B,H*W] fp16x8
                 const float* __restrict__ proj,    // [B,V,3,4]
                 const float* __restrict__ depthv,  // [B,D,H,W]
                 const float* __restrict__ regw,    // [C]
                 h2* __restrict__ pc)               // [B,D,H*W] packed (cost,dv)
{
    // swizzle: xcd = blockIdx & 7 owns a contiguous 20-band pixel group and
    // iterates all depth-pairs over it (feature reuse in its L2).
    const int i    = blockIdx.x;
    const int xcd  = i & 7;
    const int idx  = i >> 3;                        // 0..639
    const int band = xcd * BANDS_PER_XCD + (idx % BANDS_PER_XCD);
    const int dp   = idx / BANDS_PER_XCD;           // 0..31
    const int d0   = dp * 2;
    const int pixel = band * 256 + threadIdx.x;

    const int b  = (pixel >= HW) ? 1 : 0;           // uniform per block
    const int hw = pixel - b * HW;
    const int h  = hw / WW;
    const int w  = hw - h * WW;

    // reference-view features (one 16B fp16 load)
    float rf[CC], rf2[CC];
    {
        h8 rv = ft[(size_t)b * HW + hw];
#pragma unroll
        for (int c = 0; c < CC; ++c) { rf[c] = (float)rv[c]; rf2[c] = rf[c] * rf[c]; }
    }

    // per-view projection rows applied to (x, y, 1); T columns
    float Rp[2][3], Tvv[2][3];
    const float xf = (float)w, yf = (float)h;
#pragma unroll
    for (int v = 0; v < 2; ++v) {
        const float* M = proj + ((size_t)b * VV + (v + 1)) * 12;
#pragma unroll
        for (int j = 0; j < 3; ++j) {
            Rp[v][j]  = M[j * 4 + 0] * xf + M[j * 4 + 1] * yf + M[j * 4 + 2];
            Tvv[v][j] = M[j * 4 + 3];
        }
    }

    const h8* fsrc0 = ft + (size_t)(1 * BB + b) * HW;
    const h8* fsrc1 = ft + (size_t)(2 * BB + b) * HW;

    const size_t dvbase = (size_t)b * DD * HW + hw;
    const float dvA = depthv[dvbase + (size_t)d0 * HW];
    const float dvB = depthv[dvbase + (size_t)(d0 + 1) * HW];
    const float invA = __builtin_amdgcn_rcpf(dvA);
    const float invB = __builtin_amdgcn_rcpf(dvB);

    // ---- per-depth sampling geometry ----
    float wtA[2][4], wtB[2][4];
    int   ibA[2][4], ibB[2][4];
    float nmA = 1.0f, nmB = 1.0f;
#pragma unroll
    for (int v = 0; v < 2; ++v) {
#pragma unroll
        for (int pass = 0; pass < 2; ++pass) {
            const float inv_dv = pass ? invB : invA;
            float (&wt)[2][4] = pass ? wtB : wtA;
            int   (&ib)[2][4] = pass ? ibB : ibA;
            float &nm = pass ? nmB : nmA;
            const float sx = Rp[v][0] + Tvv[v][0] * inv_dv;
            const float sy = Rp[v][1] + Tvv[v][1] * inv_dv;
            const float sz = Rp[v][2] + Tvv[v][2] * inv_dv;
            const float rsz = __builtin_amdgcn_rcpf(sz);
            const float ix = sx * rsz;       // == (gx+1)*0.5*(W-1)
            const float iy = sy * rsz;
            nm += ((ix > 0.f) && (ix < (float)(WW - 1)) &&
                   (iy > 0.f) && (iy < (float)(HH - 1))) ? 1.0f : 0.0f;
            const float x0f = floorf(ix), y0f = floorf(iy);
            const float wx1 = ix - x0f, wy1 = iy - y0f;
            const float wx0 = 1.f - wx1, wy0 = 1.f - wy1;
            const float x1f = x0f + 1.f, y1f = y0f + 1.f;
            const bool vx0 = (x0f >= 0.f) && (x0f <= (float)(WW - 1));
            const bool vx1 = (x1f >= 0.f) && (x1f <= (float)(WW - 1));
            const bool vy0 = (y0f >= 0.f) && (y0f <= (float)(HH - 1));
            const bool vy1 = (y1f >= 0.f) && (y1f <= (float)(HH - 1));
            wt[v][0] = wx0 * wy0 * ((vx0 && vy0) ? 1.f : 0.f);
            wt[v][1] = wx1 * wy0 * ((vx1 && vy0) ? 1.f : 0.f);
            wt[v][2] = wx0 * wy1 * ((vx0 && vy1) ? 1.f : 0.f);
            wt[v][3] = wx1 * wy1 * ((vx1 && vy1) ? 1.f : 0.f);
            const int x0c = (int)fminf(fmaxf(x0f, 0.f), (float)(WW - 1));
            const int x1c = (int)fminf(fmaxf(x1f, 0.f), (float)(WW - 1));
            const int y0c = (int)fminf(fmaxf(y0f, 0.f), (float)(HH - 1));
            const int y1c = (int)fminf(fmaxf(y1f, 0.f), (float)(HH - 1));
            ib[v][0] = y0c * WW + x0c;
            ib[v][1] = y0c * WW + x1c;
            ib[v][2] = y1c * WW + x0c;
            ib[v][3] = y1c * WW + x1c;
        }
    }

    // ---- depth d0: load all 8 corners ----
    h8 a0 = fsrc0[ibA[0][0]];
    h8 a1 = fsrc0[ibA[0][1]];
    h8 a2 = fsrc0[ibA[0][2]];
    h8 a3 = fsrc0[ibA[0][3]];
    h8 b0 = fsrc1[ibA[1][0]];
    h8 b1 = fsrc1[ibA[1][1]];
    h8 b2 = fsrc1[ibA[1][2]];
    h8 b3 = fsrc1[ibA[1][3]];

    const size_t obase = (size_t)b * DD * HW + hw;

    {   // cost for d0
        h8 vah = a0 * splat8(wtA[0][0]) + a1 * splat8(wtA[0][1])
               + a2 * splat8(wtA[0][2]) + a3 * splat8(wtA[0][3]);
        h8 vbh = b0 * splat8(wtA[1][0]) + b1 * splat8(wtA[1][1])
               + b2 * splat8(wtA[1][2]) + b3 * splat8(wtA[1][3]);
        const float cnt = __builtin_amdgcn_rcpf(nmA);
        float t1 = 0.f, t2 = 0.f;
#pragma unroll
        for (int c = 0; c < CC; ++c) {
            const float av = (float)vah[c];
            const float bv = (float)vbh[c];
            const float sum = rf[c] + av + bv;
            const float sq  = rf2[c] + av * av + bv * bv;
            t1 += regw[c] * sq;
            t2 += (regw[c] * sum) * sum;
        }
        const float cost = cnt * t1 - (cnt * cnt) * t2;
        h2 pck; pck[0] = (_Float16)cost; pck[1] = (_Float16)dvA;
        pc[obase + (size_t)d0 * HW] = pck;
    }

    // ---- depth d0+1: reload only where corner indices changed (rare) ----
    if (ibB[0][0] != ibA[0][0] || ibB[0][3] != ibA[0][3]) {
        a0 = fsrc0[ibB[0][0]];
        a1 = fsrc0[ibB[0][1]];
        a2 = fsrc0[ibB[0][2]];
        a3 = fsrc0[ibB[0][3]];
    }
    if (ibB[1][0] != ibA[1][0] || ibB[1][3] != ibA[1][3]) {
        b0 = fsrc1[ibB[1][0]];
        b1 = fsrc1[ibB[1][1]];
        b2 = fsrc1[ibB[1][2]];
        b3 = fsrc1[ibB[1][3]];
    }

    {   // cost for d0+1
        h8 vah = a0 * splat8(wtB[0][0]) + a1 * splat8(wtB[0][1])
               + a2 * splat8(wtB[0][2]) + a3 * splat8(wtB[0][3]);
        h8 vbh = b0 * splat8(wtB[1][0]) + b1 * splat8(wtB[1][1])
               + b2 * splat8(wtB[1][2]) + b3 * splat8(wtB[1][3]);
        const float cnt = __builtin_amdgcn_rcpf(nmB);
        float t1 = 0.f, t2 = 0.f;
#pragma unroll
        for (int c = 0; c < CC; ++c) {
            const float av = (float)vah[c];
            const float bv = (float)vbh[c];
            const float sum = rf[c] + av + bv;
            const float sq  = rf2[c] + av * av + bv * bv;
            t1 += regw[c] * sq;
            t2 += (regw[c] * sum) * sum;
        }
        const float cost = cnt * t1 - (cnt * cnt) * t2;
        h2 pck; pck[0] = (_Float16)cost; pck[1] = (_Float16)dvB;
        pc[obase + (size_t)(d0 + 1) * HW] = pck;
    }
}

// ---------------------------------------------------------------------------
// Softmax-over-depth: 4 lanes/pixel x 16 depths each, packed (cost,dv) reads
// (one 4B load per depth), online softmax, shuffle merge (xor 16, 32).
// ---------------------------------------------------------------------------
__global__ __launch_bounds__(256)
void softmax_depth(const h2* __restrict__ pc,        // [B,D,H*W] packed
                   float* __restrict__ out)          // [B,H,W]
{
    const int t     = blockIdx.x * blockDim.x + threadIdx.x;
    const int lane  = t & 63;
    const int waveg = t >> 6;
    const int px    = lane & 15;
    const int chunk = lane >> 4;               // 0..3
    const int pixel = waveg * 16 + px;

    const int b  = (pixel >= HW) ? 1 : 0;
    const int hw = pixel - b * HW;

    const h2* cp = pc + (size_t)b * DD * HW + hw;

    float m = -INFINITY, l = 0.f, s = 0.f;
#pragma unroll 4
    for (int j = 0; j < 16; ++j) {
        const int d = chunk * 16 + j;
        const h2 v = cp[(size_t)d * HW];
        const float c  = (float)v[0];
        const float dv = (float)v[1];
        const float M = fmaxf(m, c);
        const float e_old = __expf(m - M);     // exp(-inf)=0 on first iter
        const float e_new = __expf(c - M);
        l = l * e_old + e_new;
        s = s * e_old + e_new * dv;
        m = M;
    }

#pragma unroll
    for (int off = 16; off < 64; off <<= 1) {
        const float m2 = __shfl_xor(m, off, 64);
        const float l2 = __shfl_xor(l, off, 64);
        const float s2 = __shfl_xor(s, off, 64);
        const float M  = fmaxf(m, m2);
        const float e1 = __expf(m - M);
        const float e2 = __expf(m2 - M);
        l = l * e1 + l2 * e2;
        s = s * e1 + s2 * e2;
        m = M;
    }

    if (chunk == 0) out[pixel] = s / l;
}

extern "C" void kernel_launch(void* const* d_in, const int* in_sizes, int n_in,
                              void* d_out, int out_size, void* d_ws, size_t ws_size,
                              hipStream_t stream) {
    const float* feats  = (const float*)d_in[0];
    const float* proj   = (const float*)d_in[1];
    const float* depthv = (const float*)d_in[2];
    const float* regw   = (const float*)d_in[3];
    float* out = (float*)d_out;
    h8* ft = (h8*)d_ws;                                       // 1.97 MB
    h2* pc = (h2*)((char*)d_ws + (size_t)VV * BB * HW * sizeof(h8));  // 10.5 MB

    {
        const int n = VV * BB * HW;                    // 122880
        hipLaunchKernelGGL(transpose_feats, dim3((n + 255) / 256), dim3(256), 0, stream,
                           feats, ft);
    }
    {
        const int grid = (DD / 2) * PIXBANDS;          // 5120 blocks
        hipLaunchKernelGGL(cost_kernel, dim3(grid), dim3(256), 0, stream,
                           ft, proj, depthv, regw, pc);
    }
    {
        const int total = NPIX * 4;                    // 4 lanes per pixel
        hipLaunchKernelGGL(softmax_depth, dim3(total / 256), dim3(256), 0, stream,
                           pc, out);
    }
}